// Round 3
// baseline (689.706 us; speedup 1.0000x reference)
//
#include <hip/hip_runtime.h>

typedef __bf16 bf16;
typedef __bf16 bf16x4 __attribute__((ext_vector_type(4)));
typedef __bf16 bf16x8 __attribute__((ext_vector_type(8)));
typedef float f32x4 __attribute__((ext_vector_type(4)));

#define NEGF (-1e9f)

// async global->LDS, 16B per lane. LDS dest must be wave-uniform-base + lane*16.
__device__ __forceinline__ void gload16(const void* g, void* l) {
  __builtin_amdgcn_global_load_lds(
      (__attribute__((address_space(1))) void*)(void*)g,
      (__attribute__((address_space(3))) void*)l, 16, 0, 0);
}

// ---------------------------------------------------------------------------
// prep: cast x and weights to bf16 (fold log2(e)/sqrt(dk) into w_q), build
// additive key-mask array; last block also computes firstone[b].
// ---------------------------------------------------------------------------
__global__ __launch_bounds__(256)
void prep_kernel(const float* __restrict__ x, const int* __restrict__ mask,
                 const float* __restrict__ wq, const float* __restrict__ wk,
                 const float* __restrict__ wv, const float* __restrict__ wo,
                 bf16* __restrict__ xb, bf16* __restrict__ wqb,
                 bf16* __restrict__ wkb, bf16* __restrict__ wvb,
                 bf16* __restrict__ wob, float* __restrict__ maskadd,
                 int* __restrict__ firstone)
{
  const float QS = 1.44269504f * 0.08838834764f;  // log2(e)/sqrt(128)
  const size_t i = ((size_t)blockIdx.x * 256 + threadIdx.x) * 4;
  if (i < (size_t)16777216) {
    const float4 v = *(const float4*)&x[i];
    bf16x4 o4 = {(bf16)v.x, (bf16)v.y, (bf16)v.z, (bf16)v.w};
    *(bf16x4*)&xb[i] = o4;
  }
  if (i < (size_t)4194304) {
    float4 v = *(const float4*)&wq[i];
    bf16x4 o4 = {(bf16)(v.x * QS), (bf16)(v.y * QS), (bf16)(v.z * QS), (bf16)(v.w * QS)};
    *(bf16x4*)&wqb[i] = o4;
    v = *(const float4*)&wk[i];
    bf16x4 o5 = {(bf16)v.x, (bf16)v.y, (bf16)v.z, (bf16)v.w};
    *(bf16x4*)&wkb[i] = o5;
    v = *(const float4*)&wv[i];
    bf16x4 o6 = {(bf16)v.x, (bf16)v.y, (bf16)v.z, (bf16)v.w};
    *(bf16x4*)&wvb[i] = o6;
    v = *(const float4*)&wo[i];
    bf16x4 o7 = {(bf16)v.x, (bf16)v.y, (bf16)v.z, (bf16)v.w};
    *(bf16x4*)&wob[i] = o7;
  }
  if (i < (size_t)8192) {
    const int4 m4 = *(const int4*)&mask[i];
    float4 o4 = {m4.x ? 0.f : NEGF, m4.y ? 0.f : NEGF,
                 m4.z ? 0.f : NEGF, m4.w ? 0.f : NEGF};
    *(float4*)&maskadd[i] = o4;
  }
  if (blockIdx.x == 16383) {   // per-batch first nonzero mask index
    __shared__ int fm;
    for (int b = 0; b < 4; ++b) {
      if (threadIdx.x == 0) fm = 2048;
      __syncthreads();
      int lm = 2048;
      for (int s = threadIdx.x; s < 2048; s += 256)
        if (mask[(b << 11) + s] != 0) lm = min(lm, s);
      atomicMin(&fm, lm);
      __syncthreads();
      if (threadIdx.x == 0) firstone[b] = fm;
      __syncthreads();
    }
  }
}

// ---------------------------------------------------------------------------
// GEMM core v2 (256x256 tile, deep pipeline, counted vmcnt — T3/T4):
// 512 threads = 8 waves (2M x 4N), per-wave output 128x64, BK=64.
// LDS 128KB: A[2][256][64] + B[2][256][64], XOR swizzle (proven 0-conflict).
// Staging of tile t+1 is issued DURING tile t in fixed order
//   B0,B2,B1,B3,A0,A2,A1,A3   (64-row groups, 1 gload16/thread/group)
// Waits derived from issue ordinals: half-0 reads need positions 1..6 of the
// previous tile -> vmcnt(2); half-1 reads need positions 7,8 which by then
// have 4 newer loads -> vmcnt(4). vmcnt never drains to 0 in the main loop.
// Last iteration re-stages tile 0 (in-bounds, never read) so the schedule
// stays uniform with NO out-of-bounds prefetch.
// ---------------------------------------------------------------------------
__device__ __forceinline__ void gemm_core256(
    const bf16* __restrict__ A, const bf16* __restrict__ Bt, const int K,
    const int rowBase, const int colBase, f32x4 acc[8][4])
{
  __shared__ __align__(16) bf16 As[2][256 * 64];
  __shared__ __align__(16) bf16 Bs[2][256 * 64];

  const int t = threadIdx.x;          // 0..511
  const int lane = t & 63;
  const int w = t >> 6;               // 0..7
  const int mh = (w >> 2) << 7;       // 0 / 128
  const int nq = (w & 3) << 6;        // 0 / 64 / 128 / 192
  const int l15 = lane & 15;
  const int quad = lane >> 4;

  // staging: group g = rows [64g, 64g+64) of the 256-row tile.
  const int srow = t >> 3;                       // row within group
  const int scol = ((t & 7) ^ (srow & 7)) << 3;  // pre-swizzled source col
  const int doff = (srow << 6) + ((t & 7) << 3); // linear LDS elem offset

  auto issueA = [&](int buf, int k0, int g) {
    gload16(&A[(size_t)(rowBase + (g << 6) + srow) * K + k0 + scol],
            &As[buf][(g << 12) + doff]);
  };
  auto issueB = [&](int buf, int k0, int g) {
    gload16(&Bt[(size_t)(colBase + (g << 6) + srow) * K + k0 + scol],
            &Bs[buf][(g << 12) + doff]);
  };

  // prologue: stage tile 0 into buf 0 in canonical order
  issueB(0, 0, 0); issueB(0, 0, 2); issueB(0, 0, 1); issueB(0, 0, 3);
  issueA(0, 0, 0); issueA(0, 0, 2); issueA(0, 0, 1); issueA(0, 0, 3);

  const int NT = K >> 6;
  for (int tt = 0; tt < NT; ++tt) {
    const int cur = tt & 1;
    const int nxt = cur ^ 1;
    // prefetch source: tile tt+1, clamped to tile 0 on the last iteration
    // (dummy, in-bounds, lands in nxt buffer which is never read again).
    const int k1 = (tt + 1 < NT) ? ((tt + 1) << 6) : 0;

    // ---- half 0: reads all B groups + A groups 0,2 of cur ----
    asm volatile("s_waitcnt vmcnt(2)" ::: "memory");
    __builtin_amdgcn_s_barrier();
    asm volatile("" ::: "memory");
    issueB(nxt, k1, 0); issueB(nxt, k1, 2);

    bf16x8 b[4][2], a[4][2];
#pragma unroll
    for (int ni = 0; ni < 4; ++ni)
#pragma unroll
      for (int ks = 0; ks < 2; ++ks) {
        const int row = nq + (ni << 4) + l15;
        b[ni][ks] = *(const bf16x8*)&Bs[cur][(row << 6) + ((((ks << 2) + quad) ^ (row & 7)) << 3)];
      }
#pragma unroll
    for (int mi = 0; mi < 4; ++mi)
#pragma unroll
      for (int ks = 0; ks < 2; ++ks) {
        const int row = mh + (mi << 4) + l15;
        a[mi][ks] = *(const bf16x8*)&As[cur][(row << 6) + ((((ks << 2) + quad) ^ (row & 7)) << 3)];
      }
    __builtin_amdgcn_s_setprio(1);
#pragma unroll
    for (int ks = 0; ks < 2; ++ks)
#pragma unroll
      for (int mi = 0; mi < 4; ++mi)
#pragma unroll
        for (int ni = 0; ni < 4; ++ni)
          acc[mi][ni] = __builtin_amdgcn_mfma_f32_16x16x32_bf16(
              a[mi][ks], b[ni][ks], acc[mi][ni], 0, 0, 0);
    __builtin_amdgcn_s_setprio(0);
    issueB(nxt, k1, 1); issueB(nxt, k1, 3);

    // ---- half 1: reads A groups 1,3 of cur ----
    asm volatile("s_waitcnt vmcnt(4)" ::: "memory");
    __builtin_amdgcn_s_barrier();
    asm volatile("" ::: "memory");
    issueA(nxt, k1, 0); issueA(nxt, k1, 2);
#pragma unroll
    for (int mi = 0; mi < 4; ++mi)
#pragma unroll
      for (int ks = 0; ks < 2; ++ks) {
        const int row = mh + 64 + (mi << 4) + l15;
        a[mi][ks] = *(const bf16x8*)&As[cur][(row << 6) + ((((ks << 2) + quad) ^ (row & 7)) << 3)];
      }
    __builtin_amdgcn_s_setprio(1);
#pragma unroll
    for (int ks = 0; ks < 2; ++ks)
#pragma unroll
      for (int mi = 0; mi < 4; ++mi)
#pragma unroll
        for (int ni = 0; ni < 4; ++ni)
          acc[mi + 4][ni] = __builtin_amdgcn_mfma_f32_16x16x32_bf16(
              a[mi][ks], b[ni][ks], acc[mi + 4][ni], 0, 0, 0);
    __builtin_amdgcn_s_setprio(0);
    issueA(nxt, k1, 1); issueA(nxt, k1, 3);
  }
  // quiesce trailing prefetch before epilogue
  asm volatile("s_waitcnt vmcnt(0)" ::: "memory");
  __builtin_amdgcn_s_barrier();
  asm volatile("" ::: "memory");
}

// QKV projection: x@W^T, epilogue scatters into per-head layouts:
//   z=0: Q -> [B,H,S,dk]   z=1: K -> [B,H,S,dk]   z=2: V -> [B,H,dk,S]
// grid 768 = 3 z * 32 my * 8 nx, XCD-chunked swizzle (768 % 8 == 0).
__global__ __launch_bounds__(512, 2)
void qkv_gemm_kernel(const bf16* __restrict__ xb,
                     const bf16* __restrict__ wqb, const bf16* __restrict__ wkb,
                     const bf16* __restrict__ wvb,
                     bf16* __restrict__ qb, bf16* __restrict__ kb,
                     bf16* __restrict__ vtb)
{
  const int id = blockIdx.x;
  const int nid = ((id & 7) * 96) + (id >> 3);   // 8 XCDs x 96 contiguous
  const int z = nid >> 8;
  const int rem = nid & 255;
  const int rowBase = (rem >> 3) << 8;
  const int colBase = (rem & 7) << 8;
  const bf16* Bt = (z == 0) ? wqb : (z == 1) ? wkb : wvb;
  bf16* dst = (z == 0) ? qb : (z == 1) ? kb : vtb;

  f32x4 acc[8][4];
#pragma unroll
  for (int mi = 0; mi < 8; ++mi)
#pragma unroll
    for (int ni = 0; ni < 4; ++ni)
#pragma unroll
      for (int r = 0; r < 4; ++r) acc[mi][ni][r] = 0.f;

  gemm_core256(xb, Bt, 2048, rowBase, colBase, acc);

  const int lane = threadIdx.x & 63;
  const int w = threadIdx.x >> 6;
  const int mh = (w >> 2) << 7;
  const int nq = (w & 3) << 6;
  const int l15 = lane & 15;
  const int quad = lane >> 4;
#pragma unroll
  for (int mi = 0; mi < 8; ++mi)
#pragma unroll
    for (int ni = 0; ni < 4; ++ni)
#pragma unroll
      for (int r = 0; r < 4; ++r) {
        const int row = rowBase + mh + (mi << 4) + (quad << 2) + r;
        const int col = colBase + nq + (ni << 4) + l15;
        const int b = row >> 11, s = row & 2047;
        const int h = col >> 7, d = col & 127;
        const bf16 v = (bf16)acc[mi][ni][r];
        if (z == 2) dst[((((b << 4) + h) << 7) + d) * 2048 + s] = v;
        else        dst[(((((b << 4) + h) << 11) + s) << 7) + d] = v;
      }
}

// final projection: attn @ w_o^T -> fp32 d_out. grid 256 = 32 my * 8 nx.
__global__ __launch_bounds__(512, 2)
void out_gemm_kernel(const bf16* __restrict__ attnb, const bf16* __restrict__ wob,
                     float* __restrict__ out)
{
  const int id = blockIdx.x;
  const int nid = ((id & 7) * 32) + (id >> 3);
  const int rowBase = (nid >> 3) << 8;
  const int colBase = (nid & 7) << 8;

  f32x4 acc[8][4];
#pragma unroll
  for (int mi = 0; mi < 8; ++mi)
#pragma unroll
    for (int ni = 0; ni < 4; ++ni)
#pragma unroll
      for (int r = 0; r < 4; ++r) acc[mi][ni][r] = 0.f;

  gemm_core256(attnb, wob, 2048, rowBase, colBase, acc);

  const int lane = threadIdx.x & 63;
  const int w = threadIdx.x >> 6;
  const int mh = (w >> 2) << 7;
  const int nq = (w & 3) << 6;
  const int l15 = lane & 15;
  const int quad = lane >> 4;
#pragma unroll
  for (int mi = 0; mi < 8; ++mi)
#pragma unroll
    for (int ni = 0; ni < 4; ++ni)
#pragma unroll
      for (int r = 0; r < 4; ++r) {
        const int row = rowBase + mh + (mi << 4) + (quad << 2) + r;
        const int col = colBase + nq + (ni << 4) + l15;
        out[((size_t)row << 11) + col] = acc[mi][ni][r];
      }
}

// ---------------------------------------------------------------------------
// flash attention, fixed-max softmax (m=0). P-transpose aliases the K-tile.
// LDS = 32KB, 4 blocks/CU co-resident (whole 1024-block grid).  [round-0
// version: the 64KB double-buffer variant cost co-residency and regressed —
// inter-block overlap at 4 blocks/CU beats intra-block dbuf.]
// ---------------------------------------------------------------------------
__global__ __launch_bounds__(256, 2)
void flash_kernel(const bf16* __restrict__ qb, const bf16* __restrict__ kb,
                  const bf16* __restrict__ vtb, const float* __restrict__ maskadd,
                  bf16* __restrict__ attnb)
{
  __shared__ __align__(16) bf16 Ks[64 * 128];   // K tile; re-used as P after QK
  __shared__ __align__(16) bf16 Vs[128 * 64];   // V^T tile

  const int h = blockIdx.y, b = blockIdx.z;
  const int qt = (b & 1) ? (int)blockIdx.x : 15 - (int)blockIdx.x;
  const int t = threadIdx.x, lane = t & 63, w = t >> 6;
  const int quad = lane >> 4, l15 = lane & 15;
  const int bh = (b << 4) + h;
  const bf16* Qp = qb + (size_t)bh * (2048 * 128);
  const bf16* Kp = kb + (size_t)bh * (2048 * 128);
  const bf16* Vp = vtb + (size_t)bh * (128 * 2048);
  const int qrow0 = (qt << 7) + (w << 5);

  // Q fragments (A layout: m=l15, k=quad*8+j), log2-scaled already
  bf16x8 qf[2][4];
#pragma unroll
  for (int mi = 0; mi < 2; ++mi)
#pragma unroll
    for (int kk = 0; kk < 4; ++kk)
      qf[mi][kk] = *(const bf16x8*)&Qp[((qrow0 + (mi << 4) + l15) << 7) + (kk << 5) + (quad << 3)];

  f32x4 o[2][8];
  float lpart[2][4];
#pragma unroll
  for (int mi = 0; mi < 2; ++mi)
#pragma unroll
    for (int r = 0; r < 4; ++r) lpart[mi][r] = 0.f;
#pragma unroll
  for (int mi = 0; mi < 2; ++mi)
#pragma unroll
    for (int dj = 0; dj < 8; ++dj)
#pragma unroll
      for (int r = 0; r < 4; ++r) o[mi][dj][r] = 0.f;

  bf16* Pw = &Ks[w << 11];   // per-wave 32x64 P region (stride 64, XOR swizzle)
  const int nkt = (qt << 1) + 2;
  for (int kt = 0; kt < nkt; ++kt) {
    __syncthreads();                        // prior P/V reads done
#pragma unroll
    for (int i = 0; i < 4; ++i) {           // K tile 64x128
      const int c = (i << 8) + t;
      const int row = c >> 4;
      const int col = ((c & 15) ^ (row & 15)) << 3;
      gload16(&Kp[(((kt << 6) + row) << 7) + col], &Ks[c << 3]);
    }
#pragma unroll
    for (int i = 0; i < 4; ++i) {           // V^T tile 128x64
      const int c = (i << 8) + t;
      const int row = c >> 3;
      const int col = ((c & 7) ^ (row & 7)) << 3;
      gload16(&Vp[(row << 11) + (kt << 6) + col], &Vs[c << 3]);
    }
    __syncthreads();                        // tiles visible

    const bool skip = (kt << 6) > qrow0 + 31;
    f32x4 S[2][4];
    if (!skip) {
      // S = Q @ K^T (log2 domain)
#pragma unroll
      for (int mi = 0; mi < 2; ++mi)
#pragma unroll
        for (int nj = 0; nj < 4; ++nj)
#pragma unroll
          for (int r = 0; r < 4; ++r) S[mi][nj][r] = 0.f;
#pragma unroll
      for (int kk = 0; kk < 4; ++kk) {
        bf16x8 kf[4];
#pragma unroll
        for (int nj = 0; nj < 4; ++nj) {
          const int key = (nj << 4) + l15;
          const int gd = (kk << 2) + quad;
          kf[nj] = *(const bf16x8*)&Ks[(key << 7) + ((gd ^ (key & 15)) << 3)];
        }
#pragma unroll
        for (int mi = 0; mi < 2; ++mi)
#pragma unroll
          for (int nj = 0; nj < 4; ++nj)
            S[mi][nj] = __builtin_amdgcn_mfma_f32_16x16x32_bf16(qf[mi][kk], kf[nj], S[mi][nj], 0, 0, 0);
      }
      // mask + causal + exp2 (m=0 fixed), accumulate l partials
      float mv[4];
#pragma unroll
      for (int nj = 0; nj < 4; ++nj)
        mv[nj] = maskadd[(b << 11) + (kt << 6) + (nj << 4) + l15];
      const bool diag = ((kt << 6) + 63 > qrow0);
#pragma unroll
      for (int mi = 0; mi < 2; ++mi)
#pragma unroll
        for (int nj = 0; nj < 4; ++nj)
#pragma unroll
          for (int r = 0; r < 4; ++r) {
            float s = S[mi][nj][r] + mv[nj];
            if (diag) {
              const int key = (kt << 6) + (nj << 4) + l15;
              const int qrow = qrow0 + (mi << 4) + (quad << 2) + r;
              if (key > qrow) s += NEGF;
            }
            const float p = __builtin_amdgcn_exp2f(s);
            S[mi][nj][r] = p;
            lpart[mi][r] += p;
          }
    }
    __syncthreads();                        // all waves done reading Ks
    if (!skip) {
      // P -> LDS (C-layout write, XOR-swizzled stride 64), wave-local
#pragma unroll
      for (int mi = 0; mi < 2; ++mi)
#pragma unroll
        for (int nj = 0; nj < 4; ++nj)
#pragma unroll
          for (int r = 0; r < 4; ++r) {
            const int row = (mi << 4) + (quad << 2) + r;
            const int col = (nj << 4) + l15;
            Pw[(row << 6) + ((((col >> 3) ^ (row & 7)) << 3) | (col & 7))] = (bf16)S[mi][nj][r];
          }
      // read back in A layout, PV mfmas
#pragma unroll
      for (int kk = 0; kk < 2; ++kk) {
        bf16x8 pf[2];
#pragma unroll
        for (int mi = 0; mi < 2; ++mi) {
          const int row = (mi << 4) + l15;
          pf[mi] = *(const bf16x8*)&Pw[(row << 6) + ((((kk << 2) + quad) ^ (row & 7)) << 3)];
        }
#pragma unroll
        for (int dj = 0; dj < 8; ++dj) {
          const int d = (dj << 4) + l15;
          const int gd = (kk << 2) + quad;
          const bf16x8 vf = *(const bf16x8*)&Vs[(d << 6) + ((gd ^ (d & 7)) << 3)];
#pragma unroll
          for (int mi = 0; mi < 2; ++mi)
            o[mi][dj] = __builtin_amdgcn_mfma_f32_16x16x32_bf16(pf[mi], vf, o[mi][dj], 0, 0, 0);
        }
      }
    }
  }

  // one-time l reduction across the 16 lanes holding each row's columns
#pragma unroll
  for (int mi = 0; mi < 2; ++mi)
#pragma unroll
    for (int r = 0; r < 4; ++r) {
      float s = lpart[mi][r];
#pragma unroll
      for (int off = 1; off < 16; off <<= 1) s += __shfl_xor(s, off);
      const float inv = 1.0f / s;   // l==0 rows produce NaN; fixup overwrites them
      const int row = qrow0 + (mi << 4) + (quad << 2) + r;
#pragma unroll
      for (int dj = 0; dj < 8; ++dj) {
        const int d = (dj << 4) + l15;
        attnb[((size_t)((b << 11) + row) << 11) + (h << 7) + d] = (bf16)(o[mi][dj][r] * inv);
      }
    }
}

// ---------------------------------------------------------------------------
// degenerate-row handling: rows q < first_nonzero(mask[b]) have ALL scores
// masked in the reference -> softmax uniform over all 2048 keys -> mean(V).
// ---------------------------------------------------------------------------
__global__ void mean_v_kernel(const bf16* __restrict__ vtb, float* __restrict__ meanv)
{
  const int row = blockIdx.x;  // bh*128 + d, 8192 rows
  float sum = 0.f;
  for (int s = threadIdx.x; s < 2048; s += 256)
    sum += (float)vtb[((size_t)row << 11) + s];
#pragma unroll
  for (int off = 1; off < 64; off <<= 1) sum += __shfl_xor(sum, off);
  __shared__ float part[4];
  if ((threadIdx.x & 63) == 0) part[threadIdx.x >> 6] = sum;
  __syncthreads();
  if (threadIdx.x == 0)
    meanv[row] = (part[0] + part[1] + part[2] + part[3]) * (1.0f / 2048.0f);
}

__global__ void fixup_kernel(const int* __restrict__ firstone,
                             const float* __restrict__ meanv,
                             bf16* __restrict__ attnb)
{
  const int b = blockIdx.x, h = blockIdx.y, d = threadIdx.x;  // 128 threads
  const int f = firstone[b];
  const bf16 v = (bf16)meanv[(((b << 4) + h) << 7) + d];
  for (int s = 0; s < f; ++s)
    attnb[((size_t)((b << 11) + s) << 11) + (h << 7) + d] = v;
}

// ---------------------------------------------------------------------------
extern "C" void kernel_launch(void* const* d_in, const int* in_sizes, int n_in,
                              void* d_out, int out_size, void* d_ws, size_t ws_size,
                              hipStream_t stream)
{
  const float* x  = (const float*)d_in[0];
  const int* mask = (const int*)d_in[1];
  const float* wq = (const float*)d_in[2];
  const float* wk = (const float*)d_in[3];
  const float* wv = (const float*)d_in[4];
  const float* wo = (const float*)d_in[5];
  float* out = (float*)d_out;

  char* ws = (char*)d_ws;
  bf16* xb      = (bf16*)(ws + 0);            // 33554432
  bf16* wqb     = (bf16*)(ws + 33554432);     //  8388608
  bf16* wkb     = (bf16*)(ws + 41943040);     //  8388608
  bf16* wvb     = (bf16*)(ws + 50331648);     //  8388608
  bf16* wob     = (bf16*)(ws + 58720256);     //  8388608
  bf16* qb      = (bf16*)(ws + 67108864);     // 33554432
  bf16* kb      = (bf16*)(ws + 100663296);    // 33554432
  bf16* vtb     = (bf16*)(ws + 134217728);    // 33554432
  bf16* attnb   = (bf16*)(ws + 167772160);    // 33554432
  float* maskadd= (float*)(ws + 201326592);   //    32768
  float* meanv  = (float*)(ws + 201359360);   //    32768
  int* firstone = (int*)(ws + 201392128);     //       16

  prep_kernel<<<16384, 256, 0, stream>>>(x, mask, wq, wk, wv, wo,
                                         xb, wqb, wkb, wvb, wob, maskadd, firstone);
  qkv_gemm_kernel<<<768, 512, 0, stream>>>(xb, wqb, wkb, wvb, qb, kb, vtb);
  mean_v_kernel<<<8192, 256, 0, stream>>>(vtb, meanv);
  flash_kernel<<<dim3(16, 16, 4), 256, 0, stream>>>(qb, kb, vtb, maskadd, attnb);
  fixup_kernel<<<dim3(4, 16), 128, 0, stream>>>(firstone, meanv, attnb);
  out_gemm_kernel<<<256, 512, 0, stream>>>(attnb, wob, out);
}

// Round 4
// 669.438 us; speedup vs baseline: 1.0303x; 1.0303x over previous
//
#include <hip/hip_runtime.h>

typedef __bf16 bf16;
typedef __bf16 bf16x4 __attribute__((ext_vector_type(4)));
typedef __bf16 bf16x8 __attribute__((ext_vector_type(8)));
typedef float f32x4 __attribute__((ext_vector_type(4)));

#define NEGF (-1e9f)

// async global->LDS, 16B per lane. LDS dest must be wave-uniform-base + lane*16.
__device__ __forceinline__ void gload16(const void* g, void* l) {
  __builtin_amdgcn_global_load_lds(
      (__attribute__((address_space(1))) void*)(void*)g,
      (__attribute__((address_space(3))) void*)l, 16, 0, 0);
}

// ---------------------------------------------------------------------------
// prep: cast x and weights to bf16 (fold log2(e)/sqrt(dk) into w_q), build
// additive key-mask array; last block also computes firstone[b].
// ---------------------------------------------------------------------------
__global__ __launch_bounds__(256)
void prep_kernel(const float* __restrict__ x, const int* __restrict__ mask,
                 const float* __restrict__ wq, const float* __restrict__ wk,
                 const float* __restrict__ wv, const float* __restrict__ wo,
                 bf16* __restrict__ xb, bf16* __restrict__ wqb,
                 bf16* __restrict__ wkb, bf16* __restrict__ wvb,
                 bf16* __restrict__ wob, float* __restrict__ maskadd,
                 int* __restrict__ firstone)
{
  const float QS = 1.44269504f * 0.08838834764f;  // log2(e)/sqrt(128)
  const size_t i = ((size_t)blockIdx.x * 256 + threadIdx.x) * 4;
  if (i < (size_t)16777216) {
    const float4 v = *(const float4*)&x[i];
    bf16x4 o4 = {(bf16)v.x, (bf16)v.y, (bf16)v.z, (bf16)v.w};
    *(bf16x4*)&xb[i] = o4;
  }
  if (i < (size_t)4194304) {
    float4 v = *(const float4*)&wq[i];
    bf16x4 o4 = {(bf16)(v.x * QS), (bf16)(v.y * QS), (bf16)(v.z * QS), (bf16)(v.w * QS)};
    *(bf16x4*)&wqb[i] = o4;
    v = *(const float4*)&wk[i];
    bf16x4 o5 = {(bf16)v.x, (bf16)v.y, (bf16)v.z, (bf16)v.w};
    *(bf16x4*)&wkb[i] = o5;
    v = *(const float4*)&wv[i];
    bf16x4 o6 = {(bf16)v.x, (bf16)v.y, (bf16)v.z, (bf16)v.w};
    *(bf16x4*)&wvb[i] = o6;
    v = *(const float4*)&wo[i];
    bf16x4 o7 = {(bf16)v.x, (bf16)v.y, (bf16)v.z, (bf16)v.w};
    *(bf16x4*)&wob[i] = o7;
  }
  if (i < (size_t)8192) {
    const int4 m4 = *(const int4*)&mask[i];
    float4 o4 = {m4.x ? 0.f : NEGF, m4.y ? 0.f : NEGF,
                 m4.z ? 0.f : NEGF, m4.w ? 0.f : NEGF};
    *(float4*)&maskadd[i] = o4;
  }
  if (blockIdx.x == 16383) {   // per-batch first nonzero mask index
    __shared__ int fm;
    for (int b = 0; b < 4; ++b) {
      if (threadIdx.x == 0) fm = 2048;
      __syncthreads();
      int lm = 2048;
      for (int s = threadIdx.x; s < 2048; s += 256)
        if (mask[(b << 11) + s] != 0) lm = min(lm, s);
      atomicMin(&fm, lm);
      __syncthreads();
      if (threadIdx.x == 0) firstone[b] = fm;
      __syncthreads();
    }
  }
}

// ---------------------------------------------------------------------------
// GEMM core v3: 256x256 tile, 8-PHASE fine interleave (m201 template).
// 512 threads = 8 waves (2M x 4N), per-wave C = 128x64, BK=64.
// LDS 128KB: A[2][2][128][64] + B[2][2][128][64]  (dbuf x half x rows x k).
// Per K-tile: 4 phases, one 32-row C-quadrant each (16 MFMA). Per phase:
//   {ds_read frags (12 at q0 / 4 else) -> stage 1 half-tile -> [vmcnt(4)]
//    -> s_barrier -> lgkmcnt(0) -> setprio(1) 16 MFMA setprio(0) -> s_barrier}
// ds_reads issue BEFORE the barrier -> barrier-wait hides LDS latency.
// Stage schedule per iter (t0=2j, t1=2j+1; stages tgt t1..t3):
//   p1: t1.A0+A1 | p3: t2.B0 | p4: t2.B1 | p5: t2.A0 | p6: t2.A1
//   p7: t3.B0    | p8: t3.B1
// Every overwrite is >=1 barrier after last read of old content (hazard-free).
// vmcnt(4) at p4 lands t1.A* (read p5-p8); at p8 lands t2.* (read next p1-p4).
// Counted vmcnt: never drains to 0 in the main loop (T4).
// ---------------------------------------------------------------------------
#define GPHASE(d, q, VM, ...)                                                   \
  {                                                                             \
    if (q == 0) {                                                               \
      _Pragma("unroll") for (int ni = 0; ni < 4; ++ni)                          \
        _Pragma("unroll") for (int ks = 0; ks < 2; ++ks) {                      \
          const int row = nq + (ni << 4) + l15;                                 \
          bfr[ni][ks] = *(const bf16x8*)&Bs[d][hB][(row << 6) +                 \
                        ((((ks << 2) + quad) ^ (row & 7)) << 3)];               \
        }                                                                       \
    }                                                                           \
    bf16x8 afr[2][2];                                                           \
    _Pragma("unroll") for (int mi = 0; mi < 2; ++mi)                            \
      _Pragma("unroll") for (int ks = 0; ks < 2; ++ks) {                        \
        const int row = (((q << 1) + mi) << 4) + l15;                           \
        afr[mi][ks] = *(const bf16x8*)&As[d][hA][(row << 6) +                   \
                      ((((ks << 2) + quad) ^ (row & 7)) << 3)];                 \
      }                                                                         \
    __VA_ARGS__;                                                                \
    if (VM) asm volatile("s_waitcnt vmcnt(4)" ::: "memory");                    \
    asm volatile("" ::: "memory");                                              \
    __builtin_amdgcn_s_barrier();                                               \
    asm volatile("s_waitcnt lgkmcnt(0)" ::: "memory");                          \
    __builtin_amdgcn_s_setprio(1);                                              \
    _Pragma("unroll") for (int ks = 0; ks < 2; ++ks)                            \
      _Pragma("unroll") for (int mi = 0; mi < 2; ++mi)                          \
        _Pragma("unroll") for (int ni = 0; ni < 4; ++ni)                        \
          acc[(q << 1) + mi][ni] = __builtin_amdgcn_mfma_f32_16x16x32_bf16(     \
              afr[mi][ks], bfr[ni][ks], acc[(q << 1) + mi][ni], 0, 0, 0);       \
    __builtin_amdgcn_s_setprio(0);                                              \
    asm volatile("" ::: "memory");                                              \
    __builtin_amdgcn_s_barrier();                                               \
    asm volatile("" ::: "memory");                                              \
  }

__device__ __forceinline__ void gemm_core256(
    const bf16* __restrict__ A, const bf16* __restrict__ Bt, const int K,
    const int rowBase, const int colBase, f32x4 acc[8][4])
{
  __shared__ __align__(16) bf16 As[2][2][128 * 64];
  __shared__ __align__(16) bf16 Bs[2][2][128 * 64];

  const int t = threadIdx.x;          // 0..511
  const int lane = t & 63;
  const int w = t >> 6;               // 0..7
  const int hA = w >> 2;              // A-half (wave-group rows 128*hA)
  const int bq = w & 3;
  const int hB = bq >> 1;             // B-half
  const int nq = (bq & 1) << 6;       // row offset within B-half
  const int l15 = lane & 15;
  const int quad = lane >> 4;

  // staging: half-tile = 128 rows x 64 k = 2 gload16/thread (64-row blocks)
  const int srow = t >> 3;                       // 0..63
  const int scol = ((t & 7) ^ (srow & 7)) << 3;  // pre-swizzled source col
  const int doff = (srow << 6) + ((t & 7) << 3); // linear LDS elem offset

  auto stA = [&](int d, int half, int kt) {
#pragma unroll
    for (int r = 0; r < 2; ++r)
      gload16(&A[(size_t)(rowBase + (half << 7) + (r << 6) + srow) * K + (kt << 6) + scol],
              &As[d][half][(r << 12) + doff]);
  };
  auto stB = [&](int d, int half, int kt) {
#pragma unroll
    for (int r = 0; r < 2; ++r)
      gload16(&Bt[(size_t)(colBase + (half << 7) + (r << 6) + srow) * K + (kt << 6) + scol],
              &Bs[d][half][(r << 12) + doff]);
  };

  // prologue: t0 fully + t1.B0,B1 ; vmcnt(4) lands all of t0
  stB(0, 0, 0); stB(0, 1, 0); stA(0, 0, 0); stA(0, 1, 0);
  stB(1, 0, 1); stB(1, 1, 1);
  asm volatile("s_waitcnt vmcnt(4)" ::: "memory");
  __builtin_amdgcn_s_barrier();
  asm volatile("" ::: "memory");

  const int NT = K >> 6;              // 32
  bf16x8 bfr[4][2];
  for (int it = 0; it < (NT >> 1); ++it) {
    const int t1 = (it << 1) + 1;                       // always < NT
    const int s2 = (t1 + 1 < NT) ? t1 + 1 : 0;          // dummy-clamped
    const int s3 = (t1 + 2 < NT) ? t1 + 2 : 0;
    // K-tile t0 in buf 0
    GPHASE(0, 0, false, stA(1, 0, t1); stA(1, 1, t1))
    GPHASE(0, 1, false, )
    GPHASE(0, 2, false, stB(0, 0, s2))
    GPHASE(0, 3, true,  stB(0, 1, s2))
    // K-tile t1 in buf 1
    GPHASE(1, 0, false, stA(0, 0, s2))
    GPHASE(1, 1, false, stA(0, 1, s2))
    GPHASE(1, 2, false, stB(1, 0, s3))
    GPHASE(1, 3, true,  stB(1, 1, s3))
  }
  // quiesce trailing prefetch before epilogue
  asm volatile("s_waitcnt vmcnt(0)" ::: "memory");
  __builtin_amdgcn_s_barrier();
  asm volatile("" ::: "memory");
}

// QKV projection: x@W^T, epilogue scatters into per-head layouts:
//   z=0: Q -> [B,H,S,dk]   z=1: K -> [B,H,S,dk]   z=2: V -> [B,H,dk,S]
// grid 768 = 3 z * 32 my * 8 nx, XCD-chunked swizzle (768 % 8 == 0).
__global__ __launch_bounds__(512, 2)
void qkv_gemm_kernel(const bf16* __restrict__ xb,
                     const bf16* __restrict__ wqb, const bf16* __restrict__ wkb,
                     const bf16* __restrict__ wvb,
                     bf16* __restrict__ qb, bf16* __restrict__ kb,
                     bf16* __restrict__ vtb)
{
  const int id = blockIdx.x;
  const int nid = ((id & 7) * 96) + (id >> 3);   // 8 XCDs x 96 contiguous
  const int z = nid >> 8;
  const int rem = nid & 255;
  const int rowBase = (rem >> 3) << 8;
  const int colBase = (rem & 7) << 8;
  const bf16* Bt = (z == 0) ? wqb : (z == 1) ? wkb : wvb;
  bf16* dst = (z == 0) ? qb : (z == 1) ? kb : vtb;

  f32x4 acc[8][4];
#pragma unroll
  for (int mi = 0; mi < 8; ++mi)
#pragma unroll
    for (int ni = 0; ni < 4; ++ni)
#pragma unroll
      for (int r = 0; r < 4; ++r) acc[mi][ni][r] = 0.f;

  gemm_core256(xb, Bt, 2048, rowBase, colBase, acc);

  const int lane = threadIdx.x & 63;
  const int w = threadIdx.x >> 6;
  const int mh = (w >> 2) << 7;
  const int nqf = (w & 3) << 6;
  const int l15 = lane & 15;
  const int quad = lane >> 4;
#pragma unroll
  for (int mi = 0; mi < 8; ++mi)
#pragma unroll
    for (int ni = 0; ni < 4; ++ni)
#pragma unroll
      for (int r = 0; r < 4; ++r) {
        const int row = rowBase + mh + (mi << 4) + (quad << 2) + r;
        const int col = colBase + nqf + (ni << 4) + l15;
        const int b = row >> 11, s = row & 2047;
        const int h = col >> 7, d = col & 127;
        const bf16 v = (bf16)acc[mi][ni][r];
        if (z == 2) dst[((((b << 4) + h) << 7) + d) * 2048 + s] = v;
        else        dst[(((((b << 4) + h) << 11) + s) << 7) + d] = v;
      }
}

// final projection: attn @ w_o^T -> fp32 d_out. grid 256 = 32 my * 8 nx.
__global__ __launch_bounds__(512, 2)
void out_gemm_kernel(const bf16* __restrict__ attnb, const bf16* __restrict__ wob,
                     float* __restrict__ out)
{
  const int id = blockIdx.x;
  const int nid = ((id & 7) * 32) + (id >> 3);
  const int rowBase = (nid >> 3) << 8;
  const int colBase = (nid & 7) << 8;

  f32x4 acc[8][4];
#pragma unroll
  for (int mi = 0; mi < 8; ++mi)
#pragma unroll
    for (int ni = 0; ni < 4; ++ni)
#pragma unroll
      for (int r = 0; r < 4; ++r) acc[mi][ni][r] = 0.f;

  gemm_core256(attnb, wob, 2048, rowBase, colBase, acc);

  const int lane = threadIdx.x & 63;
  const int w = threadIdx.x >> 6;
  const int mh = (w >> 2) << 7;
  const int nqf = (w & 3) << 6;
  const int l15 = lane & 15;
  const int quad = lane >> 4;
#pragma unroll
  for (int mi = 0; mi < 8; ++mi)
#pragma unroll
    for (int ni = 0; ni < 4; ++ni)
#pragma unroll
      for (int r = 0; r < 4; ++r) {
        const int row = rowBase + mh + (mi << 4) + (quad << 2) + r;
        const int col = colBase + nqf + (ni << 4) + l15;
        out[((size_t)row << 11) + col] = acc[mi][ni][r];
      }
}

// ---------------------------------------------------------------------------
// flash attention, fixed-max softmax (m=0). P-transpose aliases the K-tile.
// LDS = 32KB, 4 blocks/CU co-resident (whole 1024-block grid).  [round-0
// version: inter-block overlap at 4 blocks/CU beats intra-block dbuf.]
// ---------------------------------------------------------------------------
__global__ __launch_bounds__(256, 2)
void flash_kernel(const bf16* __restrict__ qb, const bf16* __restrict__ kb,
                  const bf16* __restrict__ vtb, const float* __restrict__ maskadd,
                  bf16* __restrict__ attnb)
{
  __shared__ __align__(16) bf16 Ks[64 * 128];   // K tile; re-used as P after QK
  __shared__ __align__(16) bf16 Vs[128 * 64];   // V^T tile

  const int h = blockIdx.y, b = blockIdx.z;
  const int qt = (b & 1) ? (int)blockIdx.x : 15 - (int)blockIdx.x;
  const int t = threadIdx.x, lane = t & 63, w = t >> 6;
  const int quad = lane >> 4, l15 = lane & 15;
  const int bh = (b << 4) + h;
  const bf16* Qp = qb + (size_t)bh * (2048 * 128);
  const bf16* Kp = kb + (size_t)bh * (2048 * 128);
  const bf16* Vp = vtb + (size_t)bh * (128 * 2048);
  const int qrow0 = (qt << 7) + (w << 5);

  // Q fragments (A layout: m=l15, k=quad*8+j), log2-scaled already
  bf16x8 qf[2][4];
#pragma unroll
  for (int mi = 0; mi < 2; ++mi)
#pragma unroll
    for (int kk = 0; kk < 4; ++kk)
      qf[mi][kk] = *(const bf16x8*)&Qp[((qrow0 + (mi << 4) + l15) << 7) + (kk << 5) + (quad << 3)];

  f32x4 o[2][8];
  float lpart[2][4];
#pragma unroll
  for (int mi = 0; mi < 2; ++mi)
#pragma unroll
    for (int r = 0; r < 4; ++r) lpart[mi][r] = 0.f;
#pragma unroll
  for (int mi = 0; mi < 2; ++mi)
#pragma unroll
    for (int dj = 0; dj < 8; ++dj)
#pragma unroll
      for (int r = 0; r < 4; ++r) o[mi][dj][r] = 0.f;

  bf16* Pw = &Ks[w << 11];   // per-wave 32x64 P region (stride 64, XOR swizzle)
  const int nkt = (qt << 1) + 2;
  for (int kt = 0; kt < nkt; ++kt) {
    __syncthreads();                        // prior P/V reads done
#pragma unroll
    for (int i = 0; i < 4; ++i) {           // K tile 64x128
      const int c = (i << 8) + t;
      const int row = c >> 4;
      const int col = ((c & 15) ^ (row & 15)) << 3;
      gload16(&Kp[(((kt << 6) + row) << 7) + col], &Ks[c << 3]);
    }
#pragma unroll
    for (int i = 0; i < 4; ++i) {           // V^T tile 128x64
      const int c = (i << 8) + t;
      const int row = c >> 3;
      const int col = ((c & 7) ^ (row & 7)) << 3;
      gload16(&Vp[(row << 11) + (kt << 6) + col], &Vs[c << 3]);
    }
    __syncthreads();                        // tiles visible

    const bool skip = (kt << 6) > qrow0 + 31;
    f32x4 S[2][4];
    if (!skip) {
      // S = Q @ K^T (log2 domain)
#pragma unroll
      for (int mi = 0; mi < 2; ++mi)
#pragma unroll
        for (int nj = 0; nj < 4; ++nj)
#pragma unroll
          for (int r = 0; r < 4; ++r) S[mi][nj][r] = 0.f;
#pragma unroll
      for (int kk = 0; kk < 4; ++kk) {
        bf16x8 kf[4];
#pragma unroll
        for (int nj = 0; nj < 4; ++nj) {
          const int key = (nj << 4) + l15;
          const int gd = (kk << 2) + quad;
          kf[nj] = *(const bf16x8*)&Ks[(key << 7) + ((gd ^ (key & 15)) << 3)];
        }
#pragma unroll
        for (int mi = 0; mi < 2; ++mi)
#pragma unroll
          for (int nj = 0; nj < 4; ++nj)
            S[mi][nj] = __builtin_amdgcn_mfma_f32_16x16x32_bf16(qf[mi][kk], kf[nj], S[mi][nj], 0, 0, 0);
      }
      // mask + causal + exp2 (m=0 fixed), accumulate l partials
      float mv[4];
#pragma unroll
      for (int nj = 0; nj < 4; ++nj)
        mv[nj] = maskadd[(b << 11) + (kt << 6) + (nj << 4) + l15];
      const bool diag = ((kt << 6) + 63 > qrow0);
#pragma unroll
      for (int mi = 0; mi < 2; ++mi)
#pragma unroll
        for (int nj = 0; nj < 4; ++nj)
#pragma unroll
          for (int r = 0; r < 4; ++r) {
            float s = S[mi][nj][r] + mv[nj];
            if (diag) {
              const int key = (kt << 6) + (nj << 4) + l15;
              const int qrow = qrow0 + (mi << 4) + (quad << 2) + r;
              if (key > qrow) s += NEGF;
            }
            const float p = __builtin_amdgcn_exp2f(s);
            S[mi][nj][r] = p;
            lpart[mi][r] += p;
          }
    }
    __syncthreads();                        // all waves done reading Ks
    if (!skip) {
      // P -> LDS (C-layout write, XOR-swizzled stride 64), wave-local
#pragma unroll
      for (int mi = 0; mi < 2; ++mi)
#pragma unroll
        for (int nj = 0; nj < 4; ++nj)
#pragma unroll
          for (int r = 0; r < 4; ++r) {
            const int row = (mi << 4) + (quad << 2) + r;
            const int col = (nj << 4) + l15;
            Pw[(row << 6) + ((((col >> 3) ^ (row & 7)) << 3) | (col & 7))] = (bf16)S[mi][nj][r];
          }
      // read back in A layout, PV mfmas
#pragma unroll
      for (int kk = 0; kk < 2; ++kk) {
        bf16x8 pf[2];
#pragma unroll
        for (int mi = 0; mi < 2; ++mi) {
          const int row = (mi << 4) + l15;
          pf[mi] = *(const bf16x8*)&Pw[(row << 6) + ((((kk << 2) + quad) ^ (row & 7)) << 3)];
        }
#pragma unroll
        for (int dj = 0; dj < 8; ++dj) {
          const int d = (dj << 4) + l15;
          const int gd = (kk << 2) + quad;
          const bf16x8 vf = *(const bf16x8*)&Vs[(d << 6) + ((gd ^ (d & 7)) << 3)];
#pragma unroll
          for (int mi = 0; mi < 2; ++mi)
            o[mi][dj] = __builtin_amdgcn_mfma_f32_16x16x32_bf16(pf[mi], vf, o[mi][dj], 0, 0, 0);
        }
      }
    }
  }

  // one-time l reduction across the 16 lanes holding each row's columns
#pragma unroll
  for (int mi = 0; mi < 2; ++mi)
#pragma unroll
    for (int r = 0; r < 4; ++r) {
      float s = lpart[mi][r];
#pragma unroll
      for (int off = 1; off < 16; off <<= 1) s += __shfl_xor(s, off);
      const float inv = 1.0f / s;   // l==0 rows produce NaN; fixup overwrites them
      const int row = qrow0 + (mi << 4) + (quad << 2) + r;
#pragma unroll
      for (int dj = 0; dj < 8; ++dj) {
        const int d = (dj << 4) + l15;
        attnb[((size_t)((b << 11) + row) << 11) + (h << 7) + d] = (bf16)(o[mi][dj][r] * inv);
      }
    }
}

// ---------------------------------------------------------------------------
// degenerate-row handling: rows q < first_nonzero(mask[b]) have ALL scores
// masked in the reference -> softmax uniform over all 2048 keys -> mean(V).
// ---------------------------------------------------------------------------
__global__ void mean_v_kernel(const bf16* __restrict__ vtb, float* __restrict__ meanv)
{
  const int row = blockIdx.x;  // bh*128 + d, 8192 rows
  float sum = 0.f;
  for (int s = threadIdx.x; s < 2048; s += 256)
    sum += (float)vtb[((size_t)row << 11) + s];
#pragma unroll
  for (int off = 1; off < 64; off <<= 1) sum += __shfl_xor(sum, off);
  __shared__ float part[4];
  if ((threadIdx.x & 63) == 0) part[threadIdx.x >> 6] = sum;
  __syncthreads();
  if (threadIdx.x == 0)
    meanv[row] = (part[0] + part[1] + part[2] + part[3]) * (1.0f / 2048.0f);
}

__global__ void fixup_kernel(const int* __restrict__ firstone,
                             const float* __restrict__ meanv,
                             bf16* __restrict__ attnb)
{
  const int b = blockIdx.x, h = blockIdx.y, d = threadIdx.x;  // 128 threads
  const int f = firstone[b];
  const bf16 v = (bf16)meanv[(((b << 4) + h) << 7) + d];
  for (int s = 0; s < f; ++s)
    attnb[((size_t)((b << 11) + s) << 11) + (h << 7) + d] = v;
}

// ---------------------------------------------------------------------------
extern "C" void kernel_launch(void* const* d_in, const int* in_sizes, int n_in,
                              void* d_out, int out_size, void* d_ws, size_t ws_size,
                              hipStream_t stream)
{
  const float* x  = (const float*)d_in[0];
  const int* mask = (const int*)d_in[1];
  const float* wq = (const float*)d_in[2];
  const float* wk = (const float*)d_in[3];
  const float* wv = (const float*)d_in[4];
  const float* wo = (const float*)d_in[5];
  float* out = (float*)d_out;

  char* ws = (char*)d_ws;
  bf16* xb      = (bf16*)(ws + 0);            // 33554432
  bf16* wqb     = (bf16*)(ws + 33554432);     //  8388608
  bf16* wkb     = (bf16*)(ws + 41943040);     //  8388608
  bf16* wvb     = (bf16*)(ws + 50331648);     //  8388608
  bf16* wob     = (bf16*)(ws + 58720256);     //  8388608
  bf16* qb      = (bf16*)(ws + 67108864);     // 33554432
  bf16* kb      = (bf16*)(ws + 100663296);    // 33554432
  bf16* vtb     = (bf16*)(ws + 134217728);    // 33554432
  bf16* attnb   = (bf16*)(ws + 167772160);    // 33554432
  float* maskadd= (float*)(ws + 201326592);   //    32768
  float* meanv  = (float*)(ws + 201359360);   //    32768
  int* firstone = (int*)(ws + 201392128);     //       16

  prep_kernel<<<16384, 256, 0, stream>>>(x, mask, wq, wk, wv, wo,
                                         xb, wqb, wkb, wvb, wob, maskadd, firstone);
  qkv_gemm_kernel<<<768, 512, 0, stream>>>(xb, wqb, wkb, wvb, qb, kb, vtb);
  mean_v_kernel<<<8192, 256, 0, stream>>>(vtb, meanv);
  flash_kernel<<<dim3(16, 16, 4), 256, 0, stream>>>(qb, kb, vtb, maskadd, attnb);
  fixup_kernel<<<dim3(4, 16), 128, 0, stream>>>(firstone, meanv, attnb);
  out_gemm_kernel<<<256, 512, 0, stream>>>(attnb, wob, out);
}

// Round 5
// 644.867 us; speedup vs baseline: 1.0695x; 1.0381x over previous
//
#include <hip/hip_runtime.h>

typedef __bf16 bf16;
typedef __bf16 bf16x4 __attribute__((ext_vector_type(4)));
typedef __bf16 bf16x8 __attribute__((ext_vector_type(8)));
typedef float f32x4 __attribute__((ext_vector_type(4)));

#define NEGF (-1e9f)

// async global->LDS, 16B per lane. LDS dest must be wave-uniform-base + lane*16.
__device__ __forceinline__ void gload16(const void* g, void* l) {
  __builtin_amdgcn_global_load_lds(
      (__attribute__((address_space(1))) void*)(void*)g,
      (__attribute__((address_space(3))) void*)l, 16, 0, 0);
}

// ---------------------------------------------------------------------------
// prep: cast x and weights to bf16 (fold log2(e)/sqrt(dk) into w_q), build
// additive key-mask array; last block also computes firstone[b].
// ---------------------------------------------------------------------------
__global__ __launch_bounds__(256)
void prep_kernel(const float* __restrict__ x, const int* __restrict__ mask,
                 const float* __restrict__ wq, const float* __restrict__ wk,
                 const float* __restrict__ wv, const float* __restrict__ wo,
                 bf16* __restrict__ xb, bf16* __restrict__ wqb,
                 bf16* __restrict__ wkb, bf16* __restrict__ wvb,
                 bf16* __restrict__ wob, float* __restrict__ maskadd,
                 int* __restrict__ firstone)
{
  const float QS = 1.44269504f * 0.08838834764f;  // log2(e)/sqrt(128)
  const size_t i = ((size_t)blockIdx.x * 256 + threadIdx.x) * 4;
  if (i < (size_t)16777216) {
    const float4 v = *(const float4*)&x[i];
    bf16x4 o4 = {(bf16)v.x, (bf16)v.y, (bf16)v.z, (bf16)v.w};
    *(bf16x4*)&xb[i] = o4;
  }
  if (i < (size_t)4194304) {
    float4 v = *(const float4*)&wq[i];
    bf16x4 o4 = {(bf16)(v.x * QS), (bf16)(v.y * QS), (bf16)(v.z * QS), (bf16)(v.w * QS)};
    *(bf16x4*)&wqb[i] = o4;
    v = *(const float4*)&wk[i];
    bf16x4 o5 = {(bf16)v.x, (bf16)v.y, (bf16)v.z, (bf16)v.w};
    *(bf16x4*)&wkb[i] = o5;
    v = *(const float4*)&wv[i];
    bf16x4 o6 = {(bf16)v.x, (bf16)v.y, (bf16)v.z, (bf16)v.w};
    *(bf16x4*)&wvb[i] = o6;
    v = *(const float4*)&wo[i];
    bf16x4 o7 = {(bf16)v.x, (bf16)v.y, (bf16)v.z, (bf16)v.w};
    *(bf16x4*)&wob[i] = o7;
  }
  if (i < (size_t)8192) {
    const int4 m4 = *(const int4*)&mask[i];
    float4 o4 = {m4.x ? 0.f : NEGF, m4.y ? 0.f : NEGF,
                 m4.z ? 0.f : NEGF, m4.w ? 0.f : NEGF};
    *(float4*)&maskadd[i] = o4;
  }
  if (blockIdx.x == 16383) {   // per-batch first nonzero mask index
    __shared__ int fm;
    for (int b = 0; b < 4; ++b) {
      if (threadIdx.x == 0) fm = 2048;
      __syncthreads();
      int lm = 2048;
      for (int s = threadIdx.x; s < 2048; s += 256)
        if (mask[(b << 11) + s] != 0) lm = min(lm, s);
      atomicMin(&fm, lm);
      __syncthreads();
      if (threadIdx.x == 0) firstone[b] = fm;
      __syncthreads();
    }
  }
}

// ---------------------------------------------------------------------------
// GEMM core (m103 structure): C[128x128] = A @ Bt^T, bf16 in, fp32 acc.
// 4 waves x (64x64 wave tile), mfma_f32_16x16x32_bf16 4x4 frags, BK=64.
// 16-row fragment reads + XOR swizzle -> 2 lanes/bank (free).
// [256^2 deep-pipeline attempts (r2-r4) plateaued at 690 TF vs this core's
//  977 TF; unexplained ~4000cyc/K-tile stall -> reverted to proven core.]
// ---------------------------------------------------------------------------
__device__ __forceinline__ void gemm_core128(
    const bf16* __restrict__ A, const bf16* __restrict__ Bt, int K,
    int rowBase, int colBase, bf16* As, bf16* Bs, f32x4 acc[4][4])
{
  const int t = threadIdx.x;
  const int lane = t & 63;
  const int w = t >> 6;
  const int wm = (w >> 1) << 6;   // 0 / 64
  const int wn = (w & 1) << 6;    // 0 / 64
  const int l15 = lane & 15;
  const int quad = lane >> 4;

  for (int k0 = 0; k0 < K; k0 += 64) {
    __syncthreads();
#pragma unroll
    for (int i = 0; i < 4; ++i) {           // A tile: 128x64 bf16 = 16KB
      const int c = (i << 8) + t;
      const int row = c >> 3;
      const int col = ((c & 7) ^ (row & 7)) << 3;
      gload16(&A[(size_t)(rowBase + row) * K + k0 + col], &As[c << 3]);
    }
#pragma unroll
    for (int i = 0; i < 4; ++i) {           // B tile: 128x64 bf16 = 16KB
      const int c = (i << 8) + t;
      const int row = c >> 3;
      const int col = ((c & 7) ^ (row & 7)) << 3;
      gload16(&Bt[(size_t)(colBase + row) * K + k0 + col], &Bs[c << 3]);
    }
    __syncthreads();
#pragma unroll
    for (int ks = 0; ks < 2; ++ks) {        // 2 x k=32 steps
      bf16x8 a[4], b[4];
#pragma unroll
      for (int mi = 0; mi < 4; ++mi) {
        const int row = wm + (mi << 4) + l15;
        a[mi] = *(const bf16x8*)&As[(row << 6) + ((((ks << 2) + quad) ^ (row & 7)) << 3)];
      }
#pragma unroll
      for (int ni = 0; ni < 4; ++ni) {
        const int row = wn + (ni << 4) + l15;
        b[ni] = *(const bf16x8*)&Bs[(row << 6) + ((((ks << 2) + quad) ^ (row & 7)) << 3)];
      }
#pragma unroll
      for (int mi = 0; mi < 4; ++mi)
#pragma unroll
        for (int ni = 0; ni < 4; ++ni)
          acc[mi][ni] = __builtin_amdgcn_mfma_f32_16x16x32_bf16(
              a[mi], b[ni], acc[mi][ni], 0, 0, 0);
    }
  }
}

// QKV projection: x@W^T, epilogue scatters into per-head layouts:
//   z=0: Q -> [B,H,S,dk]   z=1: K -> [B,H,S,dk]   z=2: V -> [B,H,dk,S]
// 1-D grid 3072 = 3 z * 64 rowp * 16 colp, XCD-chunked bijective swizzle
// (3072 = 8 * 384): each XCD gets 384 consecutive nids; 16 consecutive nids
// share the same A row-panel -> A re-fetch per XCD drops (T1).
__global__ __launch_bounds__(256, 2)
void qkv_gemm_kernel(const bf16* __restrict__ xb,
                     const bf16* __restrict__ wqb, const bf16* __restrict__ wkb,
                     const bf16* __restrict__ wvb,
                     bf16* __restrict__ qb, bf16* __restrict__ kb,
                     bf16* __restrict__ vtb)
{
  __shared__ __align__(16) bf16 As[128 * 64];
  __shared__ __align__(16) bf16 Bs[128 * 64];
  const int id = blockIdx.x;
  const int nid = ((id & 7) * 384) + (id >> 3);
  const int z = nid >> 10;
  const int rem = nid & 1023;
  const int rowBase = (rem >> 4) << 7;
  const int colBase = (rem & 15) << 7;
  const bf16* Bt = (z == 0) ? wqb : (z == 1) ? wkb : wvb;
  bf16* dst = (z == 0) ? qb : (z == 1) ? kb : vtb;
  f32x4 acc[4][4];
#pragma unroll
  for (int mi = 0; mi < 4; ++mi)
#pragma unroll
    for (int ni = 0; ni < 4; ++ni)
#pragma unroll
      for (int r = 0; r < 4; ++r) acc[mi][ni][r] = 0.f;

  gemm_core128(xb, Bt, 2048, rowBase, colBase, As, Bs, acc);

  const int lane = threadIdx.x & 63;
  const int w = threadIdx.x >> 6;
  const int wm = (w >> 1) << 6;
  const int wn = (w & 1) << 6;
  const int l15 = lane & 15;
  const int quad = lane >> 4;
#pragma unroll
  for (int mi = 0; mi < 4; ++mi)
#pragma unroll
    for (int ni = 0; ni < 4; ++ni)
#pragma unroll
      for (int r = 0; r < 4; ++r) {
        const int row = rowBase + wm + (mi << 4) + (quad << 2) + r;
        const int col = colBase + wn + (ni << 4) + l15;
        const int b = row >> 11, s = row & 2047;
        const int h = col >> 7, d = col & 127;
        const bf16 v = (bf16)acc[mi][ni][r];
        if (z == 2) dst[((((b << 4) + h) << 7) + d) * 2048 + s] = v;
        else        dst[(((((b << 4) + h) << 11) + s) << 7) + d] = v;
      }
}

// final projection: attn @ w_o^T -> fp32 d_out.
// 1-D grid 1024 = 64 rowp * 16 colp, XCD-chunked swizzle (1024 = 8 * 128).
__global__ __launch_bounds__(256, 2)
void out_gemm_kernel(const bf16* __restrict__ attnb, const bf16* __restrict__ wob,
                     float* __restrict__ out)
{
  __shared__ __align__(16) bf16 As[128 * 64];
  __shared__ __align__(16) bf16 Bs[128 * 64];
  const int id = blockIdx.x;
  const int nid = ((id & 7) * 128) + (id >> 3);
  const int rowBase = (nid >> 4) << 7;
  const int colBase = (nid & 15) << 7;
  f32x4 acc[4][4];
#pragma unroll
  for (int mi = 0; mi < 4; ++mi)
#pragma unroll
    for (int ni = 0; ni < 4; ++ni)
#pragma unroll
      for (int r = 0; r < 4; ++r) acc[mi][ni][r] = 0.f;

  gemm_core128(attnb, wob, 2048, rowBase, colBase, As, Bs, acc);

  const int lane = threadIdx.x & 63;
  const int w = threadIdx.x >> 6;
  const int wm = (w >> 1) << 6;
  const int wn = (w & 1) << 6;
  const int l15 = lane & 15;
  const int quad = lane >> 4;
#pragma unroll
  for (int mi = 0; mi < 4; ++mi)
#pragma unroll
    for (int ni = 0; ni < 4; ++ni)
#pragma unroll
      for (int r = 0; r < 4; ++r) {
        const int row = rowBase + wm + (mi << 4) + (quad << 2) + r;
        const int col = colBase + wn + (ni << 4) + l15;
        out[((size_t)row << 11) + col] = acc[mi][ni][r];
      }
}

// ---------------------------------------------------------------------------
// flash attention, fixed-max softmax (m=0).
// v5: P gets its OWN 16KB LDS region (no longer aliases the K-tile), which
// removes the middle barrier: the only cross-wave hazards left are the K/V
// restage (guarded by the top barrier) and tile visibility (bottom barrier).
// Barriers per k-tile: 3 -> 2. LDS 48KB; occupancy stays VGPR-limited at
// ~3 blocks/CU (48KB x 3 = 144 <= 160), so no occupancy cost.
// CU-balanced qt mapping as round-0.
// ---------------------------------------------------------------------------
__global__ __launch_bounds__(256, 2)
void flash_kernel(const bf16* __restrict__ qb, const bf16* __restrict__ kb,
                  const bf16* __restrict__ vtb, const float* __restrict__ maskadd,
                  bf16* __restrict__ attnb)
{
  __shared__ __align__(16) bf16 Ks[64 * 128];   // K tile
  __shared__ __align__(16) bf16 Vs[128 * 64];   // V^T tile
  __shared__ __align__(16) bf16 Ps[4 * 2048];   // per-wave 32x64 P regions

  const int h = blockIdx.y, b = blockIdx.z;
  const int qt = (b & 1) ? (int)blockIdx.x : 15 - (int)blockIdx.x;
  const int t = threadIdx.x, lane = t & 63, w = t >> 6;
  const int quad = lane >> 4, l15 = lane & 15;
  const int bh = (b << 4) + h;
  const bf16* Qp = qb + (size_t)bh * (2048 * 128);
  const bf16* Kp = kb + (size_t)bh * (2048 * 128);
  const bf16* Vp = vtb + (size_t)bh * (128 * 2048);
  const int qrow0 = (qt << 7) + (w << 5);

  // Q fragments (A layout: m=l15, k=quad*8+j), log2-scaled already
  bf16x8 qf[2][4];
#pragma unroll
  for (int mi = 0; mi < 2; ++mi)
#pragma unroll
    for (int kk = 0; kk < 4; ++kk)
      qf[mi][kk] = *(const bf16x8*)&Qp[((qrow0 + (mi << 4) + l15) << 7) + (kk << 5) + (quad << 3)];

  f32x4 o[2][8];
  float lpart[2][4];
#pragma unroll
  for (int mi = 0; mi < 2; ++mi)
#pragma unroll
    for (int r = 0; r < 4; ++r) lpart[mi][r] = 0.f;
#pragma unroll
  for (int mi = 0; mi < 2; ++mi)
#pragma unroll
    for (int dj = 0; dj < 8; ++dj)
#pragma unroll
      for (int r = 0; r < 4; ++r) o[mi][dj][r] = 0.f;

  bf16* Pw = &Ps[w << 11];   // wave-private 32x64 P region (stride 64, XOR swizzle)
  const int nkt = (qt << 1) + 2;
  for (int kt = 0; kt < nkt; ++kt) {
    __syncthreads();                        // prior K/V reads done
#pragma unroll
    for (int i = 0; i < 4; ++i) {           // K tile 64x128
      const int c = (i << 8) + t;
      const int row = c >> 4;
      const int col = ((c & 15) ^ (row & 15)) << 3;
      gload16(&Kp[(((kt << 6) + row) << 7) + col], &Ks[c << 3]);
    }
#pragma unroll
    for (int i = 0; i < 4; ++i) {           // V^T tile 128x64
      const int c = (i << 8) + t;
      const int row = c >> 3;
      const int col = ((c & 7) ^ (row & 7)) << 3;
      gload16(&Vp[(row << 11) + (kt << 6) + col], &Vs[c << 3]);
    }
    __syncthreads();                        // tiles visible

    const bool skip = (kt << 6) > qrow0 + 31;
    if (!skip) {
      // S = Q @ K^T (log2 domain)
      f32x4 S[2][4];
#pragma unroll
      for (int mi = 0; mi < 2; ++mi)
#pragma unroll
        for (int nj = 0; nj < 4; ++nj)
#pragma unroll
          for (int r = 0; r < 4; ++r) S[mi][nj][r] = 0.f;
#pragma unroll
      for (int kk = 0; kk < 4; ++kk) {
        bf16x8 kf[4];
#pragma unroll
        for (int nj = 0; nj < 4; ++nj) {
          const int key = (nj << 4) + l15;
          const int gd = (kk << 2) + quad;
          kf[nj] = *(const bf16x8*)&Ks[(key << 7) + ((gd ^ (key & 15)) << 3)];
        }
#pragma unroll
        for (int mi = 0; mi < 2; ++mi)
#pragma unroll
          for (int nj = 0; nj < 4; ++nj)
            S[mi][nj] = __builtin_amdgcn_mfma_f32_16x16x32_bf16(qf[mi][kk], kf[nj], S[mi][nj], 0, 0, 0);
      }
      // mask + causal + exp2 (m=0 fixed), accumulate l partials
      float mv[4];
#pragma unroll
      for (int nj = 0; nj < 4; ++nj)
        mv[nj] = maskadd[(b << 11) + (kt << 6) + (nj << 4) + l15];
      const bool diag = ((kt << 6) + 63 > qrow0);
#pragma unroll
      for (int mi = 0; mi < 2; ++mi)
#pragma unroll
        for (int nj = 0; nj < 4; ++nj)
#pragma unroll
          for (int r = 0; r < 4; ++r) {
            float s = S[mi][nj][r] + mv[nj];
            if (diag) {
              const int key = (kt << 6) + (nj << 4) + l15;
              const int qrow = qrow0 + (mi << 4) + (quad << 2) + r;
              if (key > qrow) s += NEGF;
            }
            const float p = __builtin_amdgcn_exp2f(s);
            S[mi][nj][r] = p;
            lpart[mi][r] += p;
          }
      // P -> wave-private LDS (C-layout write, XOR-swizzled stride 64).
      // No barrier needed: region is wave-local, Vs already synced above.
#pragma unroll
      for (int mi = 0; mi < 2; ++mi)
#pragma unroll
        for (int nj = 0; nj < 4; ++nj)
#pragma unroll
          for (int r = 0; r < 4; ++r) {
            const int row = (mi << 4) + (quad << 2) + r;
            const int col = (nj << 4) + l15;
            Pw[(row << 6) + ((((col >> 3) ^ (row & 7)) << 3) | (col & 7))] = (bf16)S[mi][nj][r];
          }
      // read back in A layout, PV mfmas
#pragma unroll
      for (int kk = 0; kk < 2; ++kk) {
        bf16x8 pf[2];
#pragma unroll
        for (int mi = 0; mi < 2; ++mi) {
          const int row = (mi << 4) + l15;
          pf[mi] = *(const bf16x8*)&Pw[(row << 6) + ((((kk << 2) + quad) ^ (row & 7)) << 3)];
        }
#pragma unroll
        for (int dj = 0; dj < 8; ++dj) {
          const int d = (dj << 4) + l15;
          const int gd = (kk << 2) + quad;
          const bf16x8 vf = *(const bf16x8*)&Vs[(d << 6) + ((gd ^ (d & 7)) << 3)];
#pragma unroll
          for (int mi = 0; mi < 2; ++mi)
            o[mi][dj] = __builtin_amdgcn_mfma_f32_16x16x32_bf16(pf[mi], vf, o[mi][dj], 0, 0, 0);
        }
      }
    }
  }

  // one-time l reduction across the 16 lanes holding each row's columns
#pragma unroll
  for (int mi = 0; mi < 2; ++mi)
#pragma unroll
    for (int r = 0; r < 4; ++r) {
      float s = lpart[mi][r];
#pragma unroll
      for (int off = 1; off < 16; off <<= 1) s += __shfl_xor(s, off);
      const float inv = 1.0f / s;   // l==0 rows produce NaN; fixup overwrites them
      const int row = qrow0 + (mi << 4) + (quad << 2) + r;
#pragma unroll
      for (int dj = 0; dj < 8; ++dj) {
        const int d = (dj << 4) + l15;
        attnb[((size_t)((b << 11) + row) << 11) + (h << 7) + d] = (bf16)(o[mi][dj][r] * inv);
      }
    }
}

// ---------------------------------------------------------------------------
// degenerate-row handling: rows q < first_nonzero(mask[b]) have ALL scores
// masked in the reference -> softmax uniform over all 2048 keys -> mean(V).
// ---------------------------------------------------------------------------
__global__ void mean_v_kernel(const bf16* __restrict__ vtb, float* __restrict__ meanv)
{
  const int row = blockIdx.x;  // bh*128 + d, 8192 rows
  float sum = 0.f;
  for (int s = threadIdx.x; s < 2048; s += 256)
    sum += (float)vtb[((size_t)row << 11) + s];
#pragma unroll
  for (int off = 1; off < 64; off <<= 1) sum += __shfl_xor(sum, off);
  __shared__ float part[4];
  if ((threadIdx.x & 63) == 0) part[threadIdx.x >> 6] = sum;
  __syncthreads();
  if (threadIdx.x == 0)
    meanv[row] = (part[0] + part[1] + part[2] + part[3]) * (1.0f / 2048.0f);
}

__global__ void fixup_kernel(const int* __restrict__ firstone,
                             const float* __restrict__ meanv,
                             bf16* __restrict__ attnb)
{
  const int b = blockIdx.x, h = blockIdx.y, d = threadIdx.x;  // 128 threads
  const int f = firstone[b];
  const bf16 v = (bf16)meanv[(((b << 4) + h) << 7) + d];
  for (int s = 0; s < f; ++s)
    attnb[((size_t)((b << 11) + s) << 11) + (h << 7) + d] = v;
}

// ---------------------------------------------------------------------------
extern "C" void kernel_launch(void* const* d_in, const int* in_sizes, int n_in,
                              void* d_out, int out_size, void* d_ws, size_t ws_size,
                              hipStream_t stream)
{
  const float* x  = (const float*)d_in[0];
  const int* mask = (const int*)d_in[1];
  const float* wq = (const float*)d_in[2];
  const float* wk = (const float*)d_in[3];
  const float* wv = (const float*)d_in[4];
  const float* wo = (const float*)d_in[5];
  float* out = (float*)d_out;

  char* ws = (char*)d_ws;
  bf16* xb      = (bf16*)(ws + 0);            // 33554432
  bf16* wqb     = (bf16*)(ws + 33554432);     //  8388608
  bf16* wkb     = (bf16*)(ws + 41943040);     //  8388608
  bf16* wvb     = (bf16*)(ws + 50331648);     //  8388608
  bf16* wob     = (bf16*)(ws + 58720256);     //  8388608
  bf16* qb      = (bf16*)(ws + 67108864);     // 33554432
  bf16* kb      = (bf16*)(ws + 100663296);    // 33554432
  bf16* vtb     = (bf16*)(ws + 134217728);    // 33554432
  bf16* attnb   = (bf16*)(ws + 167772160);    // 33554432
  float* maskadd= (float*)(ws + 201326592);   //    32768
  float* meanv  = (float*)(ws + 201359360);   //    32768
  int* firstone = (int*)(ws + 201392128);     //       16

  prep_kernel<<<16384, 256, 0, stream>>>(x, mask, wq, wk, wv, wo,
                                         xb, wqb, wkb, wvb, wob, maskadd, firstone);
  qkv_gemm_kernel<<<3072, 256, 0, stream>>>(xb, wqb, wkb, wvb, qb, kb, vtb);
  mean_v_kernel<<<8192, 256, 0, stream>>>(vtb, meanv);
  flash_kernel<<<dim3(16, 16, 4), 256, 0, stream>>>(qb, kb, vtb, maskadd, attnb);
  fixup_kernel<<<dim3(4, 16), 128, 0, stream>>>(firstone, meanv, attnb);
  out_gemm_kernel<<<1024, 256, 0, stream>>>(attnb, wob, out);
}

// Round 6
// 641.343 us; speedup vs baseline: 1.0754x; 1.0055x over previous
//
#include <hip/hip_runtime.h>

typedef __bf16 bf16;
typedef __bf16 bf16x4 __attribute__((ext_vector_type(4)));
typedef __bf16 bf16x8 __attribute__((ext_vector_type(8)));
typedef float f32x4 __attribute__((ext_vector_type(4)));

#define NEGF (-1e9f)

// async global->LDS, 16B per lane. LDS dest must be wave-uniform-base + lane*16.
__device__ __forceinline__ void gload16(const void* g, void* l) {
  __builtin_amdgcn_global_load_lds(
      (__attribute__((address_space(1))) void*)(void*)g,
      (__attribute__((address_space(3))) void*)l, 16, 0, 0);
}

// ---------------------------------------------------------------------------
// prep: cast x and weights to bf16 (fold log2(e)/sqrt(dk) into w_q), build
// additive key-mask array; last block also computes firstone[b].
// ---------------------------------------------------------------------------
__global__ __launch_bounds__(256)
void prep_kernel(const float* __restrict__ x, const int* __restrict__ mask,
                 const float* __restrict__ wq, const float* __restrict__ wk,
                 const float* __restrict__ wv, const float* __restrict__ wo,
                 bf16* __restrict__ xb, bf16* __restrict__ wqb,
                 bf16* __restrict__ wkb, bf16* __restrict__ wvb,
                 bf16* __restrict__ wob, float* __restrict__ maskadd,
                 int* __restrict__ firstone)
{
  const float QS = 1.44269504f * 0.08838834764f;  // log2(e)/sqrt(128)
  const size_t i = ((size_t)blockIdx.x * 256 + threadIdx.x) * 4;
  if (i < (size_t)16777216) {
    const float4 v = *(const float4*)&x[i];
    bf16x4 o4 = {(bf16)v.x, (bf16)v.y, (bf16)v.z, (bf16)v.w};
    *(bf16x4*)&xb[i] = o4;
  }
  if (i < (size_t)4194304) {
    float4 v = *(const float4*)&wq[i];
    bf16x4 o4 = {(bf16)(v.x * QS), (bf16)(v.y * QS), (bf16)(v.z * QS), (bf16)(v.w * QS)};
    *(bf16x4*)&wqb[i] = o4;
    v = *(const float4*)&wk[i];
    bf16x4 o5 = {(bf16)v.x, (bf16)v.y, (bf16)v.z, (bf16)v.w};
    *(bf16x4*)&wkb[i] = o5;
    v = *(const float4*)&wv[i];
    bf16x4 o6 = {(bf16)v.x, (bf16)v.y, (bf16)v.z, (bf16)v.w};
    *(bf16x4*)&wvb[i] = o6;
    v = *(const float4*)&wo[i];
    bf16x4 o7 = {(bf16)v.x, (bf16)v.y, (bf16)v.z, (bf16)v.w};
    *(bf16x4*)&wob[i] = o7;
  }
  if (i < (size_t)8192) {
    const int4 m4 = *(const int4*)&mask[i];
    float4 o4 = {m4.x ? 0.f : NEGF, m4.y ? 0.f : NEGF,
                 m4.z ? 0.f : NEGF, m4.w ? 0.f : NEGF};
    *(float4*)&maskadd[i] = o4;
  }
  if (blockIdx.x == 16383) {   // per-batch first nonzero mask index
    __shared__ int fm;
    for (int b = 0; b < 4; ++b) {
      if (threadIdx.x == 0) fm = 2048;
      __syncthreads();
      int lm = 2048;
      for (int s = threadIdx.x; s < 2048; s += 256)
        if (mask[(b << 11) + s] != 0) lm = min(lm, s);
      atomicMin(&fm, lm);
      __syncthreads();
      if (threadIdx.x == 0) firstone[b] = fm;
      __syncthreads();
    }
  }
}

// ---------------------------------------------------------------------------
// GEMM core (m103 structure): C[128x128] = A @ Bt^T, bf16 in, fp32 acc.
// 4 waves x (64x64 wave tile), mfma_f32_16x16x32_bf16 4x4 frags, BK=64.
// 16-row fragment reads + XOR swizzle -> 2 lanes/bank (free).
// [256^2 deep-pipeline (r2-r4) plateaued at 690 TF; XCD-chunk swizzle (r5)
//  cut FETCH 17% but cost 22% time -> both reverted. The round-0 3-D grid's
//  implicit mapping (colp round-robin over XCDs -> each XCD reuses ~2
//  L2-resident B-panels) is the measured best.]
// ---------------------------------------------------------------------------
__device__ __forceinline__ void gemm_core128(
    const bf16* __restrict__ A, const bf16* __restrict__ Bt, int K,
    int rowBase, int colBase, bf16* As, bf16* Bs, f32x4 acc[4][4])
{
  const int t = threadIdx.x;
  const int lane = t & 63;
  const int w = t >> 6;
  const int wm = (w >> 1) << 6;   // 0 / 64
  const int wn = (w & 1) << 6;    // 0 / 64
  const int l15 = lane & 15;
  const int quad = lane >> 4;

  for (int k0 = 0; k0 < K; k0 += 64) {
    __syncthreads();
#pragma unroll
    for (int i = 0; i < 4; ++i) {           // A tile: 128x64 bf16 = 16KB
      const int c = (i << 8) + t;
      const int row = c >> 3;
      const int col = ((c & 7) ^ (row & 7)) << 3;
      gload16(&A[(size_t)(rowBase + row) * K + k0 + col], &As[c << 3]);
    }
#pragma unroll
    for (int i = 0; i < 4; ++i) {           // B tile: 128x64 bf16 = 16KB
      const int c = (i << 8) + t;
      const int row = c >> 3;
      const int col = ((c & 7) ^ (row & 7)) << 3;
      gload16(&Bt[(size_t)(colBase + row) * K + k0 + col], &Bs[c << 3]);
    }
    __syncthreads();
#pragma unroll
    for (int ks = 0; ks < 2; ++ks) {        // 2 x k=32 steps
      bf16x8 a[4], b[4];
#pragma unroll
      for (int mi = 0; mi < 4; ++mi) {
        const int row = wm + (mi << 4) + l15;
        a[mi] = *(const bf16x8*)&As[(row << 6) + ((((ks << 2) + quad) ^ (row & 7)) << 3)];
      }
#pragma unroll
      for (int ni = 0; ni < 4; ++ni) {
        const int row = wn + (ni << 4) + l15;
        b[ni] = *(const bf16x8*)&Bs[(row << 6) + ((((ks << 2) + quad) ^ (row & 7)) << 3)];
      }
#pragma unroll
      for (int mi = 0; mi < 4; ++mi)
#pragma unroll
        for (int ni = 0; ni < 4; ++ni)
          acc[mi][ni] = __builtin_amdgcn_mfma_f32_16x16x32_bf16(
              a[mi], b[ni], acc[mi][ni], 0, 0, 0);
    }
  }
}

// one projection: x@W^T. vmode=0: dst[B,H,S,dk]; vmode=1: dst[B,H,dk,S].
// Launched once per {Q,K,V} so each dispatch (~70us) sorts BELOW flash
// (~250us) in the profile -> flash's counters become visible.
__global__ __launch_bounds__(256, 2)
void proj_gemm_kernel(const bf16* __restrict__ xb, const bf16* __restrict__ Bt,
                      bf16* __restrict__ dst, const int vmode)
{
  __shared__ __align__(16) bf16 As[128 * 64];
  __shared__ __align__(16) bf16 Bs[128 * 64];
  const int rowBase = blockIdx.y << 7;
  const int colBase = blockIdx.x << 7;
  f32x4 acc[4][4];
#pragma unroll
  for (int mi = 0; mi < 4; ++mi)
#pragma unroll
    for (int ni = 0; ni < 4; ++ni)
#pragma unroll
      for (int r = 0; r < 4; ++r) acc[mi][ni][r] = 0.f;

  gemm_core128(xb, Bt, 2048, rowBase, colBase, As, Bs, acc);

  const int lane = threadIdx.x & 63;
  const int w = threadIdx.x >> 6;
  const int wm = (w >> 1) << 6;
  const int wn = (w & 1) << 6;
  const int l15 = lane & 15;
  const int quad = lane >> 4;
#pragma unroll
  for (int mi = 0; mi < 4; ++mi)
#pragma unroll
    for (int ni = 0; ni < 4; ++ni)
#pragma unroll
      for (int r = 0; r < 4; ++r) {
        const int row = rowBase + wm + (mi << 4) + (quad << 2) + r;
        const int col = colBase + wn + (ni << 4) + l15;
        const int b = row >> 11, s = row & 2047;
        const int h = col >> 7, d = col & 127;
        const bf16 v = (bf16)acc[mi][ni][r];
        if (vmode) dst[((((b << 4) + h) << 7) + d) * 2048 + s] = v;
        else       dst[(((((b << 4) + h) << 11) + s) << 7) + d] = v;
      }
}

// final projection: attn @ w_o^T -> fp32 d_out. round-0 3-D grid mapping.
__global__ __launch_bounds__(256, 2)
void out_gemm_kernel(const bf16* __restrict__ attnb, const bf16* __restrict__ wob,
                     float* __restrict__ out)
{
  __shared__ __align__(16) bf16 As[128 * 64];
  __shared__ __align__(16) bf16 Bs[128 * 64];
  const int rowBase = blockIdx.y << 7;
  const int colBase = blockIdx.x << 7;
  f32x4 acc[4][4];
#pragma unroll
  for (int mi = 0; mi < 4; ++mi)
#pragma unroll
    for (int ni = 0; ni < 4; ++ni)
#pragma unroll
      for (int r = 0; r < 4; ++r) acc[mi][ni][r] = 0.f;

  gemm_core128(attnb, wob, 2048, rowBase, colBase, As, Bs, acc);

  const int lane = threadIdx.x & 63;
  const int w = threadIdx.x >> 6;
  const int wm = (w >> 1) << 6;
  const int wn = (w & 1) << 6;
  const int l15 = lane & 15;
  const int quad = lane >> 4;
#pragma unroll
  for (int mi = 0; mi < 4; ++mi)
#pragma unroll
    for (int ni = 0; ni < 4; ++ni)
#pragma unroll
      for (int r = 0; r < 4; ++r) {
        const int row = rowBase + wm + (mi << 4) + (quad << 2) + r;
        const int col = colBase + wn + (ni << 4) + l15;
        out[((size_t)row << 11) + col] = acc[mi][ni][r];
      }
}

// ---------------------------------------------------------------------------
// flash attention, fixed-max softmax (m=0). v6 = v5 (wave-private P region,
// 2 barriers/k-tile, 48KB LDS) + T5 setprio around MFMA clusters: flash has
// 4 independent blocks/CU at uncorrelated phases -> the regime where setprio
// measured +4-7% (m191), unlike barrier-locked GEMM waves.
// ---------------------------------------------------------------------------
__global__ __launch_bounds__(256, 2)
void flash_kernel(const bf16* __restrict__ qb, const bf16* __restrict__ kb,
                  const bf16* __restrict__ vtb, const float* __restrict__ maskadd,
                  bf16* __restrict__ attnb)
{
  __shared__ __align__(16) bf16 Ks[64 * 128];   // K tile
  __shared__ __align__(16) bf16 Vs[128 * 64];   // V^T tile
  __shared__ __align__(16) bf16 Ps[4 * 2048];   // per-wave 32x64 P regions

  const int h = blockIdx.y, b = blockIdx.z;
  const int qt = (b & 1) ? (int)blockIdx.x : 15 - (int)blockIdx.x;
  const int t = threadIdx.x, lane = t & 63, w = t >> 6;
  const int quad = lane >> 4, l15 = lane & 15;
  const int bh = (b << 4) + h;
  const bf16* Qp = qb + (size_t)bh * (2048 * 128);
  const bf16* Kp = kb + (size_t)bh * (2048 * 128);
  const bf16* Vp = vtb + (size_t)bh * (128 * 2048);
  const int qrow0 = (qt << 7) + (w << 5);

  // Q fragments (A layout: m=l15, k=quad*8+j), log2-scaled already
  bf16x8 qf[2][4];
#pragma unroll
  for (int mi = 0; mi < 2; ++mi)
#pragma unroll
    for (int kk = 0; kk < 4; ++kk)
      qf[mi][kk] = *(const bf16x8*)&Qp[((qrow0 + (mi << 4) + l15) << 7) + (kk << 5) + (quad << 3)];

  f32x4 o[2][8];
  float lpart[2][4];
#pragma unroll
  for (int mi = 0; mi < 2; ++mi)
#pragma unroll
    for (int r = 0; r < 4; ++r) lpart[mi][r] = 0.f;
#pragma unroll
  for (int mi = 0; mi < 2; ++mi)
#pragma unroll
    for (int dj = 0; dj < 8; ++dj)
#pragma unroll
      for (int r = 0; r < 4; ++r) o[mi][dj][r] = 0.f;

  bf16* Pw = &Ps[w << 11];   // wave-private 32x64 P region (stride 64, XOR swizzle)
  const int nkt = (qt << 1) + 2;
  for (int kt = 0; kt < nkt; ++kt) {
    __syncthreads();                        // prior K/V reads done
#pragma unroll
    for (int i = 0; i < 4; ++i) {           // K tile 64x128
      const int c = (i << 8) + t;
      const int row = c >> 4;
      const int col = ((c & 15) ^ (row & 15)) << 3;
      gload16(&Kp[(((kt << 6) + row) << 7) + col], &Ks[c << 3]);
    }
#pragma unroll
    for (int i = 0; i < 4; ++i) {           // V^T tile 128x64
      const int c = (i << 8) + t;
      const int row = c >> 3;
      const int col = ((c & 7) ^ (row & 7)) << 3;
      gload16(&Vp[(row << 11) + (kt << 6) + col], &Vs[c << 3]);
    }
    __syncthreads();                        // tiles visible

    const bool skip = (kt << 6) > qrow0 + 31;
    if (!skip) {
      // S = Q @ K^T (log2 domain)
      f32x4 S[2][4];
#pragma unroll
      for (int mi = 0; mi < 2; ++mi)
#pragma unroll
        for (int nj = 0; nj < 4; ++nj)
#pragma unroll
          for (int r = 0; r < 4; ++r) S[mi][nj][r] = 0.f;
      __builtin_amdgcn_s_setprio(1);
#pragma unroll
      for (int kk = 0; kk < 4; ++kk) {
        bf16x8 kf[4];
#pragma unroll
        for (int nj = 0; nj < 4; ++nj) {
          const int key = (nj << 4) + l15;
          const int gd = (kk << 2) + quad;
          kf[nj] = *(const bf16x8*)&Ks[(key << 7) + ((gd ^ (key & 15)) << 3)];
        }
#pragma unroll
        for (int mi = 0; mi < 2; ++mi)
#pragma unroll
          for (int nj = 0; nj < 4; ++nj)
            S[mi][nj] = __builtin_amdgcn_mfma_f32_16x16x32_bf16(qf[mi][kk], kf[nj], S[mi][nj], 0, 0, 0);
      }
      __builtin_amdgcn_s_setprio(0);
      // mask + causal + exp2 (m=0 fixed), accumulate l partials
      float mv[4];
#pragma unroll
      for (int nj = 0; nj < 4; ++nj)
        mv[nj] = maskadd[(b << 11) + (kt << 6) + (nj << 4) + l15];
      const bool diag = ((kt << 6) + 63 > qrow0);
#pragma unroll
      for (int mi = 0; mi < 2; ++mi)
#pragma unroll
        for (int nj = 0; nj < 4; ++nj)
#pragma unroll
          for (int r = 0; r < 4; ++r) {
            float s = S[mi][nj][r] + mv[nj];
            if (diag) {
              const int key = (kt << 6) + (nj << 4) + l15;
              const int qrow = qrow0 + (mi << 4) + (quad << 2) + r;
              if (key > qrow) s += NEGF;
            }
            const float p = __builtin_amdgcn_exp2f(s);
            S[mi][nj][r] = p;
            lpart[mi][r] += p;
          }
      // P -> wave-private LDS (C-layout write, XOR-swizzled stride 64).
      // No barrier needed: region is wave-local, Vs already synced above.
#pragma unroll
      for (int mi = 0; mi < 2; ++mi)
#pragma unroll
        for (int nj = 0; nj < 4; ++nj)
#pragma unroll
          for (int r = 0; r < 4; ++r) {
            const int row = (mi << 4) + (quad << 2) + r;
            const int col = (nj << 4) + l15;
            Pw[(row << 6) + ((((col >> 3) ^ (row & 7)) << 3) | (col & 7))] = (bf16)S[mi][nj][r];
          }
      // read back in A layout, PV mfmas
#pragma unroll
      for (int kk = 0; kk < 2; ++kk) {
        bf16x8 pf[2];
#pragma unroll
        for (int mi = 0; mi < 2; ++mi) {
          const int row = (mi << 4) + l15;
          pf[mi] = *(const bf16x8*)&Pw[(row << 6) + ((((kk << 2) + quad) ^ (row & 7)) << 3)];
        }
        __builtin_amdgcn_s_setprio(1);
#pragma unroll
        for (int dj = 0; dj < 8; ++dj) {
          const int d = (dj << 4) + l15;
          const int gd = (kk << 2) + quad;
          const bf16x8 vf = *(const bf16x8*)&Vs[(d << 6) + ((gd ^ (d & 7)) << 3)];
#pragma unroll
          for (int mi = 0; mi < 2; ++mi)
            o[mi][dj] = __builtin_amdgcn_mfma_f32_16x16x32_bf16(pf[mi], vf, o[mi][dj], 0, 0, 0);
        }
        __builtin_amdgcn_s_setprio(0);
      }
    }
  }

  // one-time l reduction across the 16 lanes holding each row's columns
#pragma unroll
  for (int mi = 0; mi < 2; ++mi)
#pragma unroll
    for (int r = 0; r < 4; ++r) {
      float s = lpart[mi][r];
#pragma unroll
      for (int off = 1; off < 16; off <<= 1) s += __shfl_xor(s, off);
      const float inv = 1.0f / s;   // l==0 rows produce NaN; fixup overwrites them
      const int row = qrow0 + (mi << 4) + (quad << 2) + r;
#pragma unroll
      for (int dj = 0; dj < 8; ++dj) {
        const int d = (dj << 4) + l15;
        attnb[((size_t)((b << 11) + row) << 11) + (h << 7) + d] = (bf16)(o[mi][dj][r] * inv);
      }
    }
}

// ---------------------------------------------------------------------------
// degenerate-row handling: rows q < first_nonzero(mask[b]) have ALL scores
// masked in the reference -> softmax uniform over all 2048 keys -> mean(V).
// ---------------------------------------------------------------------------
__global__ void mean_v_kernel(const bf16* __restrict__ vtb, float* __restrict__ meanv)
{
  const int row = blockIdx.x;  // bh*128 + d, 8192 rows
  float sum = 0.f;
  for (int s = threadIdx.x; s < 2048; s += 256)
    sum += (float)vtb[((size_t)row << 11) + s];
#pragma unroll
  for (int off = 1; off < 64; off <<= 1) sum += __shfl_xor(sum, off);
  __shared__ float part[4];
  if ((threadIdx.x & 63) == 0) part[threadIdx.x >> 6] = sum;
  __syncthreads();
  if (threadIdx.x == 0)
    meanv[row] = (part[0] + part[1] + part[2] + part[3]) * (1.0f / 2048.0f);
}

__global__ void fixup_kernel(const int* __restrict__ firstone,
                             const float* __restrict__ meanv,
                             bf16* __restrict__ attnb)
{
  const int b = blockIdx.x, h = blockIdx.y, d = threadIdx.x;  // 128 threads
  const int f = firstone[b];
  const bf16 v = (bf16)meanv[(((b << 4) + h) << 7) + d];
  for (int s = 0; s < f; ++s)
    attnb[((size_t)((b << 11) + s) << 11) + (h << 7) + d] = v;
}

// ---------------------------------------------------------------------------
extern "C" void kernel_launch(void* const* d_in, const int* in_sizes, int n_in,
                              void* d_out, int out_size, void* d_ws, size_t ws_size,
                              hipStream_t stream)
{
  const float* x  = (const float*)d_in[0];
  const int* mask = (const int*)d_in[1];
  const float* wq = (const float*)d_in[2];
  const float* wk = (const float*)d_in[3];
  const float* wv = (const float*)d_in[4];
  const float* wo = (const float*)d_in[5];
  float* out = (float*)d_out;

  char* ws = (char*)d_ws;
  bf16* xb      = (bf16*)(ws + 0);            // 33554432
  bf16* wqb     = (bf16*)(ws + 33554432);     //  8388608
  bf16* wkb     = (bf16*)(ws + 41943040);     //  8388608
  bf16* wvb     = (bf16*)(ws + 50331648);     //  8388608
  bf16* wob     = (bf16*)(ws + 58720256);     //  8388608
  bf16* qb      = (bf16*)(ws + 67108864);     // 33554432
  bf16* kb      = (bf16*)(ws + 100663296);    // 33554432
  bf16* vtb     = (bf16*)(ws + 134217728);    // 33554432
  bf16* attnb   = (bf16*)(ws + 167772160);    // 33554432
  float* maskadd= (float*)(ws + 201326592);   //    32768
  float* meanv  = (float*)(ws + 201359360);   //    32768
  int* firstone = (int*)(ws + 201392128);     //       16

  prep_kernel<<<16384, 256, 0, stream>>>(x, mask, wq, wk, wv, wo,
                                         xb, wqb, wkb, wvb, wob, maskadd, firstone);
  proj_gemm_kernel<<<dim3(16, 64), 256, 0, stream>>>(xb, wqb, qb, 0);
  proj_gemm_kernel<<<dim3(16, 64), 256, 0, stream>>>(xb, wkb, kb, 0);
  proj_gemm_kernel<<<dim3(16, 64), 256, 0, stream>>>(xb, wvb, vtb, 1);
  mean_v_kernel<<<8192, 256, 0, stream>>>(vtb, meanv);
  flash_kernel<<<dim3(16, 16, 4), 256, 0, stream>>>(qb, kb, vtb, maskadd, attnb);
  fixup_kernel<<<dim3(4, 16), 128, 0, stream>>>(firstone, meanv, attnb);
  out_gemm_kernel<<<dim3(16, 64), 256, 0, stream>>>(attnb, wob, out);
}